// Round 7
// baseline (241.364 us; speedup 1.0000x reference)
//
#include <hip/hip_runtime.h>
#include <hip/hip_bf16.h>
#include <stdint.h>

// Problem constants (B,T,C,NH,LEVEL) = (2,2048,1024,16,3)
#define B_    2
#define T_    2048
#define CD    1024
#define NH_   16
#define HS_   64
#define NSETS 511        // sum_{l=3..11} 2048>>l
#define NSP   512        // padded
#define QKV_LD 3072
#define NEGBIG (-3.4e38f)

typedef __attribute__((ext_vector_type(8))) short  short8;
typedef __attribute__((ext_vector_type(4))) float  f32x4;

__device__ __forceinline__ unsigned short f2bf(float f) {
  unsigned u = __float_as_uint(f);
  unsigned r = 0x7FFFu + ((u >> 16) & 1u);   // round-to-nearest-even
  return (unsigned short)((u + r) >> 16);
}
__device__ __forceinline__ float bf2f(unsigned short h) {
  return __uint_as_float(((unsigned)h) << 16);
}
__device__ __forceinline__ float elu1(float x) {  // elu(x)+1
  return x > 0.f ? x + 1.f : __expf(x);
}
__device__ __forceinline__ void gload16(const unsigned short* g, short* l) {
  __builtin_amdgcn_global_load_lds(
      (const __attribute__((address_space(1))) unsigned int*)g,
      (__attribute__((address_space(3))) unsigned int*)l, 16, 0, 0);
}

// ---------------- K1: fused splits -----------------------------------------
// x -> hi/lo; Wa rows 0..2047 (q,k) -> hi/lo; Wa rows 2048.. (v) -> hi only;
// Wp -> hi only.
__global__ __launch_bounds__(256) void split3_kernel(
    const float* __restrict__ x, const float* __restrict__ Wa,
    const float* __restrict__ Wp,
    unsigned short* __restrict__ xh, unsigned short* __restrict__ xl,
    unsigned short* __restrict__ wah, unsigned short* __restrict__ wal,
    unsigned short* __restrict__ wph) {
  int bid = blockIdx.x;
  const float* src; unsigned short *hi, *lo; int base;
  if (bid < 16384)      { src = x;  hi = xh;  lo = xl;  base = bid; }
  else if (bid < 24576) { src = Wa; hi = wah; lo = wal; base = bid - 16384; }
  else if (bid < 28672) { src = Wa; hi = wah; lo = nullptr; base = bid - 16384; }
  else                  { src = Wp; hi = wph; lo = nullptr; base = bid - 28672; }
  int i = base * 256 + threadIdx.x;
  float v = src[i];
  unsigned short h = f2bf(v);
  hi[i] = h;
  if (lo) lo[i] = f2bf(v - bf2f(h));
}

// ---------------- GEMM body: C[128x128 tile] = A*B^T (bf16 MFMA) ----------
// m97 structure: global_load_lds width=16 staging, 2-barrier K-loop.
template<int SPLIT>
__device__ __forceinline__ void gemm_body(
    short* lds,
    const unsigned short* __restrict__ Ah, const unsigned short* __restrict__ Al,
    const unsigned short* __restrict__ Bh, const unsigned short* __restrict__ Bl,
    float* __restrict__ Cmat, int K, int ldc, int row0, int col0)
{
  const int tid  = threadIdx.x;
  const int lane = tid & 63;
  const int w    = tid >> 6;
  const int wr   = w >> 1, wc = w & 1;

  f32x4 acc[4][4];
  #pragma unroll
  for (int a = 0; a < 4; ++a)
    #pragma unroll
    for (int b = 0; b < 4; ++b)
      acc[a][b] = (f32x4){0.f, 0.f, 0.f, 0.f};

  const int rlane = lane & 15;
  const int kgrp  = lane >> 4;                       // 0..3 (16B chunk)
  const int rsw   = (kgrp ^ (rlane & 3) ^ ((rlane >> 2) & 3)) << 4;

  // staging: lane l -> row l>>2, chunk l&3 (linear LDS dest)
  const int slr = lane >> 2;                         // row within 16-row block
  const int sch = (lane & 3) ^ (slr & 3) ^ ((slr >> 2) & 3);

  const unsigned short* ssrc;
  size_t srb;
  short* sbase;
  if (SPLIT) {
    ssrc = (w == 0) ? Ah : (w == 1) ? Bh : (w == 2) ? Al : Bl;
    srb  = (w & 1) ? (size_t)col0 : (size_t)row0;
    sbase = &lds[w * 4096];
  } else {
    ssrc = (w & 1) ? Bh : Ah;
    srb  = (w & 1) ? (size_t)col0 : (size_t)row0;
    sbase = &lds[(w & 1) * 4096 + (w >> 1) * 2048];  // half-tile per wave
    srb += (size_t)(w >> 1) * 64;
  }

  for (int kt = 0; kt < K; kt += 32) {
    __syncthreads();
    const unsigned short* g0 = ssrc + (srb + slr) * K + kt + (sch << 3);
    if (SPLIT) {
      #pragma unroll
      for (int i = 0; i < 8; ++i)
        gload16(g0 + (size_t)i * 16 * K, sbase + i * 512);
    } else {
      #pragma unroll
      for (int i = 0; i < 4; ++i)
        gload16(g0 + (size_t)i * 16 * K, sbase + i * 512);
    }
    __syncthreads();   // compiler drains vmcnt(0) here

    short8 aH[4], bH[4], aL[4], bL[4];
    #pragma unroll
    for (int m = 0; m < 4; ++m) {
      int r    = wr * 64 + m * 16 + rlane;
      int cidx = wc * 64 + m * 16 + rlane;
      aH[m] = *(const short8*)((const char*)lds + r * 64 + rsw);
      bH[m] = *(const short8*)((const char*)lds + 8192 + cidx * 64 + rsw);
      if (SPLIT) {
        aL[m] = *(const short8*)((const char*)lds + 16384 + r * 64 + rsw);
        bL[m] = *(const short8*)((const char*)lds + 24576 + cidx * 64 + rsw);
      }
    }
    #pragma unroll
    for (int mm = 0; mm < 4; ++mm)
      #pragma unroll
      for (int nn = 0; nn < 4; ++nn) {
        acc[mm][nn] = __builtin_amdgcn_mfma_f32_16x16x32_bf16(aH[mm], bH[nn], acc[mm][nn], 0, 0, 0);
        if (SPLIT) {
          acc[mm][nn] = __builtin_amdgcn_mfma_f32_16x16x32_bf16(aH[mm], bL[nn], acc[mm][nn], 0, 0, 0);
          acc[mm][nn] = __builtin_amdgcn_mfma_f32_16x16x32_bf16(aL[mm], bH[nn], acc[mm][nn], 0, 0, 0);
        }
      }
  }

  const int rl = (lane >> 4) * 4;
  const int cl = lane & 15;
  #pragma unroll
  for (int mm = 0; mm < 4; ++mm)
    #pragma unroll
    for (int nn = 0; nn < 4; ++nn)
      #pragma unroll
      for (int r = 0; r < 4; ++r) {
        int row = row0 + wr * 64 + mm * 16 + rl + r;
        int col = col0 + wc * 64 + nn * 16 + cl;
        Cmat[(size_t)row * ldc + col] = acc[mm][nn][r];
      }
}

// ---------------- K2: merged qkv GEMM --------------------------------------
// 768 blocks: bid%3 in {0,1} -> split-precision q,k tile (512 of them),
// bid%3==2 -> plain-bf16 v tile (256). Every XCD gets the 2:1 mix.
__global__ __launch_bounds__(256) void gemm_qkv(
    const unsigned short* __restrict__ xh, const unsigned short* __restrict__ xl,
    const unsigned short* __restrict__ wah, const unsigned short* __restrict__ wal,
    float* __restrict__ qkv)
{
  __shared__ short lds[4 * 4096];
  int bid = blockIdx.x;               // 768
  int t3  = bid % 3;
  if (t3 < 2) {
    int s = (bid / 3) * 2 + t3;       // 0..511
    int bx = s & 15, by = s >> 4;     // 16 x 32 tiles over N=2048
    gemm_body<1>(lds, xh, xl, wah, wal, qkv,
                 CD, QKV_LD, by * 128, bx * 128);
  } else {
    int p = bid / 3;                  // 0..255
    int bx = p & 7, by = p >> 3;      // 8 x 32 tiles over N=1024
    gemm_body<0>(lds, xh, nullptr, wah + (size_t)2048 * CD, nullptr,
                 qkv + 2048, CD, QKV_LD, by * 128, bx * 128);
  }
}

// ---------------- K7: standalone projection GEMM ---------------------------
template<int SPLIT>
__global__ __launch_bounds__(256) void gemm_bt(
    const unsigned short* __restrict__ Ah, const unsigned short* __restrict__ Al,
    const unsigned short* __restrict__ Bh, const unsigned short* __restrict__ Bl,
    float* __restrict__ Cmat, int M, int N, int K, int ldc)
{
  constexpr int NT = SPLIT ? 4 : 2;
  __shared__ short lds[NT * 4096];
  const int nwg = gridDim.x;
  const int cpx = nwg >> 3;
  const int bid = blockIdx.x;
  const int swb = (bid & 7) * cpx + (bid >> 3);
  const int nbx = N >> 7;
  const int bx = swb % nbx;
  const int by = swb / nbx;
  gemm_body<SPLIT>(lds, Ah, Al, Bh, Bl, Cmat, K, ldc, by * 128, bx * 128);
}

// ---------------- K3a: per-seg partial sums (32-row segments) --------------
__global__ __launch_bounds__(256) void cs_part(const float* __restrict__ qkv,
                                               float* __restrict__ part) {
  int blk = blockIdx.x;                 // B*64*2 = 256
  int q   = blk & 1;
  int seg = (blk >> 1) & 63;
  int b   = blk >> 7;
  int c   = threadIdx.x * 4;            // 0..1023
  const float* src = qkv + (size_t)(b * T_ + seg * 32) * QKV_LD + CD + q * CD + c;
  float4 s = {0.f, 0.f, 0.f, 0.f};
  #pragma unroll 4
  for (int j = 0; j < 32; ++j) {
    float4 v = *(const float4*)(src + (size_t)j * QKV_LD);
    if (q == 0) {
      s.x += elu1(v.x); s.y += elu1(v.y); s.z += elu1(v.z); s.w += elu1(v.w);
    } else {
      s.x += v.x; s.y += v.y; s.z += v.z; s.w += v.w;
    }
  }
  *(float4*)(part + ((size_t)(b * 64 + seg) * 2048) + q * 1024 + c) = s;
}

// ---------------- K3b: exclusive prefix over 64 segs (reg-pipelined) ------
__global__ void cs_prefix(float* __restrict__ part) {
  int idx = blockIdx.x * 256 + threadIdx.x;      // B*2048 = 4096
  int b  = idx >> 11;
  int cc = idx & 2047;
  float v[64];
  #pragma unroll
  for (int s = 0; s < 64; ++s) v[s] = part[(size_t)(b * 64 + s) * 2048 + cc];
  float run = 0.f;
  #pragma unroll
  for (int s = 0; s < 64; ++s) { float t = v[s]; v[s] = run; run += t; }
  #pragma unroll
  for (int s = 0; s < 64; ++s) part[(size_t)(b * 64 + s) * 2048 + cc] = v[s];
}

// ---------------- K3c: final walk -> kcum / vcum --------------------------
__global__ __launch_bounds__(256) void cs_final(const float* __restrict__ qkv,
                                                const float* __restrict__ part,
                                                float* __restrict__ kcum,
                                                float* __restrict__ vcum) {
  int blk = blockIdx.x;                 // 256
  int q   = blk & 1;
  int seg = (blk >> 1) & 63;
  int b   = blk >> 7;
  int c   = threadIdx.x * 4;
  int h   = c >> 6, d = c & 63;
  const float* src = qkv + (size_t)(b * T_ + seg * 32) * QKV_LD + CD + q * CD + c;
  float* dst = (q == 0 ? kcum : vcum) + ((size_t)(b * NH_ + h) * T_ + seg * 32) * HS_ + d;
  float4 s = *(const float4*)(part + ((size_t)(b * 64 + seg) * 2048) + q * 1024 + c);
  #pragma unroll 4
  for (int j = 0; j < 32; ++j) {
    float4 v = *(const float4*)(src + (size_t)j * QKV_LD);
    if (q == 0) {
      s.x += elu1(v.x); s.y += elu1(v.y); s.z += elu1(v.z); s.w += elu1(v.w);
    } else {
      s.x += v.x; s.y += v.y; s.z += v.z; s.w += v.w;
    }
    *(float4*)(dst + (size_t)j * HS_) = s;
  }
}

// ---------------- K4: sorted-by-r set aggregates ---------------------------
__global__ void build_sets(const float* __restrict__ kcum, const float* __restrict__ vcum,
                           unsigned short* __restrict__ Ksh, unsigned short* __restrict__ Ksl,
                           float* __restrict__ Vs, int* __restrict__ r_srt) {
  int idx = blockIdx.x * 256 + threadIdx.x;    // B*NH*512*64
  if (idx >= B_ * NH_ * NSP * HS_) return;
  int d  = idx & 63;
  int s  = (idx >> 6) & (NSP - 1);
  int bh = idx >> (6 + 9);
  if (s == NSETS) {                            // padding entry
    size_t o = ((size_t)(bh << 9) + s) * HS_ + d;
    Ksh[o] = 0; Ksl[o] = 0; Vs[o] = 0.f;
    if (bh == 0 && d == 0) r_srt[s] = 0x7fffffff;
    return;
  }
  int lvl = 3, base = 0;
  while (s >= base + (T_ >> lvl)) { base += T_ >> lvl; ++lvl; }
  int i  = s - base;
  int m  = (i + 1) << lvl;
  int r  = m - 1;
  int li = i << lvl;
  int rank = lvl - 3;
  #pragma unroll
  for (int j = 3; j <= 11; ++j) rank += (m - 8) >> j;

  size_t rowr = ((size_t)bh * T_ + r) * HS_ + d;
  float kr = kcum[rowr], vr = vcum[rowr];
  if (li > 0) {
    size_t rowl = ((size_t)bh * T_ + li - 1) * HS_ + d;
    kr -= kcum[rowl];
    vr -= vcum[rowl];
  }
  size_t o = ((size_t)(bh << 9) + rank) * HS_ + d;
  unsigned short kh = f2bf(kr);
  Ksh[o] = kh;
  Ksl[o] = f2bf(kr - bf2f(kh));
  Vs[o]  = vr;
  if (bh == 0 && d == 0) r_srt[rank] = r;
}

// ---------------- K4b: Vst[bh][d][512] bf16 = transpose(Vs) ---------------
__global__ __launch_bounds__(256) void vst_transpose(
    const float* __restrict__ Vs, unsigned short* __restrict__ Vst) {
  __shared__ float tile[64][65];
  int bh = blockIdx.x >> 3;
  int s0 = (blockIdx.x & 7) * 64;
  int tid = threadIdx.x;
  int srow = tid >> 2, c0 = (tid & 3) * 16;
  const float* src = Vs + ((size_t)(bh << 9) + s0 + srow) * HS_ + c0;
  #pragma unroll
  for (int j = 0; j < 4; ++j) {
    float4 v = *(const float4*)(src + j * 4);
    tile[srow][c0 + j*4 + 0] = v.x; tile[srow][c0 + j*4 + 1] = v.y;
    tile[srow][c0 + j*4 + 2] = v.z; tile[srow][c0 + j*4 + 3] = v.w;
  }
  __syncthreads();
  int d = tid >> 2, sq = (tid & 3) * 16;
  short8 a, b;
  #pragma unroll
  for (int j = 0; j < 8; ++j) {
    a[j] = (short)f2bf(tile[sq + j][d]);
    b[j] = (short)f2bf(tile[sq + 8 + j][d]);
  }
  unsigned short* dst = Vst + ((size_t)(bh << 6) + d) * NSP + s0 + sq;
  *(short8*)dst = a;
  *(short8*)(dst + 8) = b;
}

// ---------------- K5: MFMA flash attention, 128 q-rows per block ----------
// 512 blocks = 32 bh x 16 row-blocks. Q hi/lo fragments in REGISTERS
// (each lane's A-row is col-determined). K/V staged once per tile, amortized
// over 128 rows. Defer-max softmax (THR=8), deferred cross-lane sum.
__global__ __launch_bounds__(256) void attn_mfma(
    const float* __restrict__ qkv, const float* __restrict__ kcum,
    const float* __restrict__ vcum,
    const unsigned short* __restrict__ Ksh, const unsigned short* __restrict__ Ksl,
    const unsigned short* __restrict__ Vst, const int* __restrict__ r_srt,
    unsigned short* __restrict__ attnb)
{
  __shared__ short Pl[4 * 2048];        // 4 waves x 32 rows x 64 bf16 = 16KB
  __shared__ short KV[3 * 4096];        // Ksh|Ksl|Vst tiles, 8KB each
  __shared__ int   rs_lds[NSP];

  const int blk = blockIdx.x;           // 512
  const int xcd = blk & 7;
  const int j   = blk >> 3;             // 0..63
  const int bhx = j >> 4;
  const int bh  = xcd * 4 + bhx;
  const int rb  = ((j & 15) + bhx * 4) & 15;
  const int b = bh >> 4, h = bh & 15;
  const int t0 = rb * 128;
  const int tid = threadIdx.x;
  const int lane = tid & 63;
  const int w = tid >> 6;
  const int col = lane & 15;
  const int kgrp = (lane >> 4) * 8;
  const float scale = 0.125f;

  // staging geometry: per wave 6 gload16; lane l -> row i*8+(l>>3),
  // pre-swizzled source chunk ((l&7)^(l>>3)); LDS dest linear
  const int srow = lane >> 3;
  const int scsw = ((lane & 7) ^ srow) * 8;

  auto stage_tile = [&](int s0) {
    #pragma unroll
    for (int L = w * 6; L < w * 6 + 6; ++L) {
      int a = L >> 3, i = L & 7;
      const unsigned short* src;
      if (a == 0)      src = Ksh + ((size_t)(bh << 9) + s0 + i * 8 + srow) * 64 + scsw;
      else if (a == 1) src = Ksl + ((size_t)(bh << 9) + s0 + i * 8 + srow) * 64 + scsw;
      else             src = Vst + ((size_t)(bh << 6) + i * 8 + srow) * NSP + s0 + scsw;
      gload16(src, KV + a * 4096 + i * 512 + lane * 8);
    }
  };

  // ---- Q fragments: global -> split bf16 hi/lo in registers ----
  short8 qh[2][2], ql[2][2];
  #pragma unroll
  for (int rr = 0; rr < 2; ++rr) {
    int qrow = t0 + w * 32 + rr * 16 + col;
    const float* qr = qkv + (size_t)(b * T_ + qrow) * QKV_LD + h * HS_;
    #pragma unroll
    for (int ks = 0; ks < 2; ++ks) {
      float4 v0 = *(const float4*)(qr + kgrp + ks * 32);
      float4 v1 = *(const float4*)(qr + kgrp + ks * 32 + 4);
      float vv[8] = {v0.x, v0.y, v0.z, v0.w, v1.x, v1.y, v1.z, v1.w};
      #pragma unroll
      for (int jj = 0; jj < 8; ++jj) {
        unsigned short hi = f2bf(vv[jj]);
        qh[rr][ks][jj] = (short)hi;
        ql[rr][ks][jj] = (short)f2bf(vv[jj] - bf2f(hi));
      }
    }
  }
  for (int s = tid; s < NSP; s += 256) rs_lds[s] = r_srt[s];

  int rows[2][4];
  #pragma unroll
  for (int rr = 0; rr < 2; ++rr)
    #pragma unroll
    for (int r = 0; r < 4; ++r)
      rows[rr][r] = t0 + w * 32 + rr * 16 + (lane >> 4) * 4 + r;

  f32x4 O[2][4];
  float mrun[2][4], lsum[2][4];
  #pragma unroll
  for (int rr = 0; rr < 2; ++rr)
    #pragma unroll
    for (int f = 0; f < 4; ++f) {
      O[rr][f] = (f32x4){0.f, 0.f, 0.f, 0.f};
      mrun[rr][f] = NEGBIG; lsum[rr][f] = 0.f;
    }

  int nmax = 0;
  #pragma unroll
  for (int jj = 3; jj <= 11; ++jj) nmax += (t0 + 128) >> jj;
  const int ntiles = (nmax + 63) >> 6;

  for (int tile = 0; tile < ntiles; ++tile) {
    const int s0 = tile * 64;
    stage_tile(s0);
    __syncthreads();     // drains gload vmcnt(0)

    f32x4 S[2][4];
    #pragma unroll
    for (int rr = 0; rr < 2; ++rr)
      #pragma unroll
      for (int f = 0; f < 4; ++f) S[rr][f] = (f32x4){0.f, 0.f, 0.f, 0.f};

    #pragma unroll
    for (int ks = 0; ks < 2; ++ks) {
      int chnk = (lane >> 4) + ks * 4;
      #pragma unroll
      for (int f = 0; f < 4; ++f) {
        int so = f * 16 + col;
        int kb = so * 128 + ((chnk ^ (so & 7)) << 4);
        short8 bHv = *(const short8*)((const char*)KV + kb);
        short8 bLv = *(const short8*)((const char*)KV + 8192 + kb);
        #pragma unroll
        for (int rr = 0; rr < 2; ++rr) {
          S[rr][f] = __builtin_amdgcn_mfma_f32_16x16x32_bf16(qh[rr][ks], bHv, S[rr][f], 0, 0, 0);
          S[rr][f] = __builtin_amdgcn_mfma_f32_16x16x32_bf16(qh[rr][ks], bLv, S[rr][f], 0, 0, 0);
          S[rr][f] = __builtin_amdgcn_mfma_f32_16x16x32_bf16(ql[rr][ks], bHv, S[rr][f], 0, 0, 0);
        }
      }
    }

    int rsv[4];
    #pragma unroll
    for (int f = 0; f < 4; ++f) rsv[f] = rs_lds[s0 + f * 16 + col];

    // masked logits in place
    #pragma unroll
    for (int rr = 0; rr < 2; ++rr)
      #pragma unroll
      for (int f = 0; f < 4; ++f)
        #pragma unroll
        for (int r = 0; r < 4; ++r)
          S[rr][f][r] = (rsv[f] > rows[rr][r]) ? NEGBIG : S[rr][f][r] * scale;

    // ---- fast-path check across all 8 row-groups ----
    float mx[2][4];
    int pred = 1;
    #pragma unroll
    for (int rr = 0; rr < 2; ++rr)
      #pragma unroll
      for (int r = 0; r < 4; ++r) {
        mx[rr][r] = fmaxf(fmaxf(S[rr][0][r], S[rr][1][r]),
                          fmaxf(S[rr][2][r], S[rr][3][r]));
        pred &= (mx[rr][r] <= mrun[rr][r] + 8.f);
      }
    if (!__all(pred)) {
      #pragma unroll
      for (int rr = 0; rr < 2; ++rr)
        #pragma unroll
        for (int r = 0; r < 4; ++r) {
          float mt = mx[rr][r];
          mt = fmaxf(mt, __shfl_xor(mt, 1));
          mt = fmaxf(mt, __shfl_xor(mt, 2));
          mt = fmaxf(mt, __shfl_xor(mt, 4));
          mt = fmaxf(mt, __shfl_xor(mt, 8));
          float mv = fmaxf(mrun[rr][r], mt);
          float fs = __expf(mrun[rr][r] - mv);
          lsum[rr][r] *= fs;
          #pragma unroll
          for (int f = 0; f < 4; ++f) O[rr][f][r] *= fs;
          mrun[rr][r] = mv;
        }
    }

    // ---- P = exp(z - mrun), masked; lane-local sum; bf16 to LDS ----
    char* pw = (char*)Pl + w * 4096;
    #pragma unroll
    for (int rr = 0; rr < 2; ++rr)
      #pragma unroll
      for (int r = 0; r < 4; ++r) {
        int rowr = rr * 16 + (lane >> 4) * 4 + r;
        int rswz = (rowr & 7) << 4;
        #pragma unroll
        for (int f = 0; f < 4; ++f) {
          float p = __expf(S[rr][f][r] - mrun[rr][r]);
          p = (rsv[f] > rows[rr][r]) ? 0.f : p;
          lsum[rr][r] += p;
          int addr = (rowr * 128 + (f * 16 + col) * 2) ^ rswz;
          *(unsigned short*)(pw + addr) = f2bf(p);
        }
      }

    // ---- PV MFMA ----
    #pragma unroll
    for (int ks = 0; ks < 2; ++ks) {
      int chnk = (lane >> 4) + ks * 4;
      int pb0 = (col * 128 + (kgrp + ks * 32) * 2) ^ ((col & 7) << 4);
      short8 pa0 = *(const short8*)(pw + pb0);
      short8 pa1 = *(const short8*)(pw + 2048 + pb0);   // rows 16..31
      #pragma unroll
      for (int f = 0; f < 4; ++f) {
        int dr = f * 16 + col;
        short8 bv = *(const short8*)((const char*)KV + 16384 + dr * 128 + ((chnk ^ (dr & 7)) << 4));
        O[0][f] = __builtin_amdgcn_mfma_f32_16x16x32_bf16(pa0, bv, O[0][f], 0, 0, 0);
        O[1][f] = __builtin_amdgcn_mfma_f32_16x16x32_bf16(pa1, bv, O[1][f], 0, 0, 0);
      }
    }

    __syncthreads();     // all waves done reading KV before next stage
  }

  // ---- deferred cross-lane sum of lsum -> lrun ----
  float lrun[2][4];
  #pragma unroll
  for (int rr = 0; rr < 2; ++rr)
    #pragma unroll
    for (int r = 0; r < 4; ++r) {
      float l = lsum[rr][r];
      l += __shfl_xor(l, 1);
      l += __shfl_xor(l, 2);
      l += __shfl_xor(l, 4);
      l += __shfl_xor(l, 8);
      lrun[rr][r] = l;
    }

  // ---- tail term: interval [t&~7, t] with q_phi, per-row VALU ----
  float ztail[2];
  #pragma unroll
  for (int rr = 0; rr < 2; ++rr) {
    int trow = lane >> 2;
    int t = t0 + w * 32 + rr * 16 + trow;
    int d0 = (lane & 3) * 16;
    const float* qr = qkv + (size_t)(b * T_ + t) * QKV_LD + h * HS_ + d0;
    float qv[16];
    #pragma unroll
    for (int jj = 0; jj < 4; ++jj) {
      float4 v = *(const float4*)(qr + jj * 4);
      qv[jj*4+0] = v.x; qv[jj*4+1] = v.y; qv[jj*4+2] = v.z; qv[jj*4+3] = v.w;
    }
    int lt = t & ~7;
    const float* kc1 = kcum + ((size_t)bh * T_ + t) * HS_ + d0;
    float kt[16];
    if (lt > 0) {
      const float* kc0 = kcum + ((size_t)bh * T_ + (lt - 1)) * HS_ + d0;
      #pragma unroll
      for (int jj = 0; jj < 16; ++jj) kt[jj] = kc1[jj] - kc0[jj];
    } else {
      #pragma unroll
      for (int jj = 0; jj < 16; ++jj) kt[jj] = kc1[jj];
    }
    float z = 0.f;
    #pragma unroll
    for (int jj = 0; jj < 16; ++jj) {
      float qp = qv[jj] > 0.f ? qv[jj] + 1.f : __expf(qv[jj]);
      z += qp * kt[jj];
    }
    z += __shfl_xor(z, 1);
    z += __shfl_xor(z, 2);
    ztail[rr] = z * scale;
  }

  #pragma unroll
  for (int rr = 0; rr < 2; ++rr)
    #pragma unroll
    for (int r = 0; r < 4; ++r) {
      float zt = __shfl(ztail[rr], ((lane >> 4) * 4 + r) * 4);
      float mv = fmaxf(mrun[rr][r], zt);
      float fs = __expf(mrun[rr][r] - mv);     // mrun=NEGBIG -> 0
      float pwgt = __expf(zt - mv);
      lrun[rr][r] = lrun[rr][r] * fs + pwgt;
      int tr = rows[rr][r];
      int ltr = tr & ~7;
      #pragma unroll
      for (int f = 0; f < 4; ++f) {
        int d = f * 16 + col;
        float v1 = vcum[((size_t)bh * T_ + tr) * HS_ + d];
        float vt = (ltr > 0) ? v1 - vcum[((size_t)bh * T_ + (ltr - 1)) * HS_ + d] : v1;
        O[rr][f][r] = O[rr][f][r] * fs + pwgt * vt;
      }
    }

  #pragma unroll
  for (int rr = 0; rr < 2; ++rr)
    #pragma unroll
    for (int r = 0; r < 4; ++r) {
      float inv = 1.f / lrun[rr][r];
      unsigned short* orow = attnb + (size_t)(b * T_ + rows[rr][r]) * CD + h * HS_;
      #pragma unroll
      for (int f = 0; f < 4; ++f)
        orow[f * 16 + col] = f2bf(O[rr][f][r] * inv);
    }
}

// --------------------------------------------------------------------------
extern "C" void kernel_launch(void* const* d_in, const int* in_sizes, int n_in,
                              void* d_out, int out_size, void* d_ws, size_t ws_size,
                              hipStream_t stream) {
  const float* x  = (const float*)d_in[0];   // [B,T,C]
  const float* Wa = (const float*)d_in[1];   // [3C,C]
  const float* Wp = (const float*)d_in[2];   // [C,C]
  float* out = (float*)d_out;                // [B,T,C]

  char* ws = (char*)d_ws;
  size_t off = 0;
  auto alloc = [&](size_t bytes) -> char* {
    char* p = ws + off;
    off += (bytes + 255) & ~(size_t)255;
    return p;
  };

  const int M = B_ * T_;                     // 4096
  float* qkv  = (float*)alloc((size_t)M * QKV_LD * 4);            // 50.3 MB
  float* kcum = (float*)alloc((size_t)B_ * NH_ * T_ * HS_ * 4);   // 16.8 MB
  float* vcum = (float*)alloc((size_t)B_ * NH_ * T_ * HS_ * 4);   // 16.8 MB
  float* part = (float*)alloc((size_t)B_ * 64 * 2048 * 4);        // 1 MB
  unsigned short* wph = (unsigned short*)alloc((size_t)CD * CD * 2);

  // regionA: x_hi/x_lo (live through gemm_qkv), then sorted set arrays
  char* regionA = alloc((size_t)16777216);
  unsigned short* xh = (unsigned short*)regionA;
  unsigned short* xl = (unsigned short*)(regionA + (size_t)M * CD * 2);
  const size_t SETS_ELEMS = (size_t)B_ * NH_ * NSP * HS_;          // 2M
  unsigned short* Ksh = (unsigned short*)regionA;                  // 4 MB
  unsigned short* Ksl = Ksh + SETS_ELEMS;                          // 4 MB
  float*          Vss = (float*)(regionA + 2 * SETS_ELEMS * 2);    // 8 MB
  unsigned short* Vst = (unsigned short*)(regionA + 2 * SETS_ELEMS * 2 + SETS_ELEMS * 4);
  int*            r_srt = (int*)(regionA + 2 * SETS_ELEMS * 2 + SETS_ELEMS * 4 + SETS_ELEMS * 2);

  // regionB: Wa_hi/Wa_lo (live through gemm_qkv), then attn bf16 output
  char* regionB = alloc((size_t)12582912);
  unsigned short* wah = (unsigned short*)regionB;
  unsigned short* wal = (unsigned short*)(regionB + (size_t)3 * CD * CD * 2);
  unsigned short* attnb = (unsigned short*)regionB;

  // K1: fused splits (Wa v-rows get hi only)
  split3_kernel<<<dim3(32768), dim3(256), 0, stream>>>(
      x, Wa, Wp, xh, xl, wah, wal, wph);

  // K2: merged qkv GEMM (split q,k + plain v, 768 blocks)
  gemm_qkv<<<dim3(768), dim3(256), 0, stream>>>(xh, xl, wah, wal, qkv);

  // K3: phi + cumsums (32-row segments, 256 blocks each)
  cs_part<<<dim3(B_ * 64 * 2), dim3(256), 0, stream>>>(qkv, part);
  cs_prefix<<<dim3(B_ * 2048 / 256), dim3(256), 0, stream>>>(part);
  cs_final<<<dim3(B_ * 64 * 2), dim3(256), 0, stream>>>(qkv, part, kcum, vcum);

  // K4: sorted set aggregates (reuses regionA — xh/xl dead after gemm_qkv)
  build_sets<<<dim3((B_ * NH_ * NSP * HS_) / 256), dim3(256), 0, stream>>>(
      kcum, vcum, Ksh, Ksl, Vss, r_srt);
  vst_transpose<<<dim3(B_ * NH_ * (NSP / 64)), dim3(256), 0, stream>>>(Vss, Vst);

  // K5: MFMA attention, 128 rows/block (writes bf16 into regionB)
  attn_mfma<<<dim3(512), dim3(256), 0, stream>>>(
      qkv, kcum, vcum, Ksh, Ksl, Vst, r_srt, attnb);

  // K7: out = attn @ Wp^T
  gemm_bt<0><<<dim3((CD / 128) * (M / 128)), dim3(256), 0, stream>>>(
      attnb, (const unsigned short*)nullptr, wph, (const unsigned short*)nullptr,
      out, M, CD, CD, CD);
}

// Round 8
// 226.982 us; speedup vs baseline: 1.0634x; 1.0634x over previous
//
#include <hip/hip_runtime.h>
#include <hip/hip_bf16.h>
#include <stdint.h>

// Problem constants (B,T,C,NH,LEVEL) = (2,2048,1024,16,3)
#define B_    2
#define T_    2048
#define CD    1024
#define NH_   16
#define HS_   64
#define NSETS 511        // sum_{l=3..11} 2048>>l
#define NSP   512        // padded
#define QKV_LD 3072
#define NEGBIG (-3.4e38f)

typedef __attribute__((ext_vector_type(8))) short  short8;
typedef __attribute__((ext_vector_type(4))) float  f32x4;

__device__ __forceinline__ unsigned short f2bf(float f) {
  unsigned u = __float_as_uint(f);
  unsigned r = 0x7FFFu + ((u >> 16) & 1u);   // round-to-nearest-even
  return (unsigned short)((u + r) >> 16);
}
__device__ __forceinline__ float bf2f(unsigned short h) {
  return __uint_as_float(((unsigned)h) << 16);
}
__device__ __forceinline__ float elu1(float x) {  // elu(x)+1
  return x > 0.f ? x + 1.f : __expf(x);
}
__device__ __forceinline__ void gload16(const unsigned short* g, short* l) {
  __builtin_amdgcn_global_load_lds(
      (const __attribute__((address_space(1))) unsigned int*)g,
      (__attribute__((address_space(3))) unsigned int*)l, 16, 0, 0);
}

// ---------------- K1: fused splits -----------------------------------------
// x -> hi/lo; Wa rows 0..2047 (q,k) -> hi/lo; Wa rows 2048.. (v) -> hi only;
// Wp -> hi only.
__global__ __launch_bounds__(256) void split3_kernel(
    const float* __restrict__ x, const float* __restrict__ Wa,
    const float* __restrict__ Wp,
    unsigned short* __restrict__ xh, unsigned short* __restrict__ xl,
    unsigned short* __restrict__ wah, unsigned short* __restrict__ wal,
    unsigned short* __restrict__ wph) {
  int bid = blockIdx.x;
  const float* src; unsigned short *hi, *lo; int base;
  if (bid < 16384)      { src = x;  hi = xh;  lo = xl;  base = bid; }
  else if (bid < 24576) { src = Wa; hi = wah; lo = wal; base = bid - 16384; }
  else if (bid < 28672) { src = Wa; hi = wah; lo = nullptr; base = bid - 16384; }
  else                  { src = Wp; hi = wph; lo = nullptr; base = bid - 28672; }
  int i = base * 256 + threadIdx.x;
  float v = src[i];
  unsigned short h = f2bf(v);
  hi[i] = h;
  if (lo) lo[i] = f2bf(v - bf2f(h));
}

// ---------------- GEMM body: C[128x128 tile] = A*B^T (bf16 MFMA) ----------
// m97 structure: global_load_lds width=16 staging, 2-barrier K-loop.
template<int SPLIT>
__device__ __forceinline__ void gemm_body(
    short* lds,
    const unsigned short* __restrict__ Ah, const unsigned short* __restrict__ Al,
    const unsigned short* __restrict__ Bh, const unsigned short* __restrict__ Bl,
    float* __restrict__ Cmat, int K, int ldc, int row0, int col0)
{
  const int tid  = threadIdx.x;
  const int lane = tid & 63;
  const int w    = tid >> 6;
  const int wr   = w >> 1, wc = w & 1;

  f32x4 acc[4][4];
  #pragma unroll
  for (int a = 0; a < 4; ++a)
    #pragma unroll
    for (int b = 0; b < 4; ++b)
      acc[a][b] = (f32x4){0.f, 0.f, 0.f, 0.f};

  const int rlane = lane & 15;
  const int kgrp  = lane >> 4;                       // 0..3 (16B chunk)
  const int rsw   = (kgrp ^ (rlane & 3) ^ ((rlane >> 2) & 3)) << 4;

  // staging: lane l -> row l>>2, chunk l&3 (linear LDS dest)
  const int slr = lane >> 2;                         // row within 16-row block
  const int sch = (lane & 3) ^ (slr & 3) ^ ((slr >> 2) & 3);

  const unsigned short* ssrc;
  size_t srb;
  short* sbase;
  if (SPLIT) {
    ssrc = (w == 0) ? Ah : (w == 1) ? Bh : (w == 2) ? Al : Bl;
    srb  = (w & 1) ? (size_t)col0 : (size_t)row0;
    sbase = &lds[w * 4096];
  } else {
    ssrc = (w & 1) ? Bh : Ah;
    srb  = (w & 1) ? (size_t)col0 : (size_t)row0;
    sbase = &lds[(w & 1) * 4096 + (w >> 1) * 2048];  // half-tile per wave
    srb += (size_t)(w >> 1) * 64;
  }

  for (int kt = 0; kt < K; kt += 32) {
    __syncthreads();
    const unsigned short* g0 = ssrc + (srb + slr) * K + kt + (sch << 3);
    if (SPLIT) {
      #pragma unroll
      for (int i = 0; i < 8; ++i)
        gload16(g0 + (size_t)i * 16 * K, sbase + i * 512);
    } else {
      #pragma unroll
      for (int i = 0; i < 4; ++i)
        gload16(g0 + (size_t)i * 16 * K, sbase + i * 512);
    }
    __syncthreads();   // compiler drains vmcnt(0) here

    short8 aH[4], bH[4], aL[4], bL[4];
    #pragma unroll
    for (int m = 0; m < 4; ++m) {
      int r    = wr * 64 + m * 16 + rlane;
      int cidx = wc * 64 + m * 16 + rlane;
      aH[m] = *(const short8*)((const char*)lds + r * 64 + rsw);
      bH[m] = *(const short8*)((const char*)lds + 8192 + cidx * 64 + rsw);
      if (SPLIT) {
        aL[m] = *(const short8*)((const char*)lds + 16384 + r * 64 + rsw);
        bL[m] = *(const short8*)((const char*)lds + 24576 + cidx * 64 + rsw);
      }
    }
    #pragma unroll
    for (int mm = 0; mm < 4; ++mm)
      #pragma unroll
      for (int nn = 0; nn < 4; ++nn) {
        acc[mm][nn] = __builtin_amdgcn_mfma_f32_16x16x32_bf16(aH[mm], bH[nn], acc[mm][nn], 0, 0, 0);
        if (SPLIT) {
          acc[mm][nn] = __builtin_amdgcn_mfma_f32_16x16x32_bf16(aH[mm], bL[nn], acc[mm][nn], 0, 0, 0);
          acc[mm][nn] = __builtin_amdgcn_mfma_f32_16x16x32_bf16(aL[mm], bH[nn], acc[mm][nn], 0, 0, 0);
        }
      }
  }

  const int rl = (lane >> 4) * 4;
  const int cl = lane & 15;
  #pragma unroll
  for (int mm = 0; mm < 4; ++mm)
    #pragma unroll
    for (int nn = 0; nn < 4; ++nn)
      #pragma unroll
      for (int r = 0; r < 4; ++r) {
        int row = row0 + wr * 64 + mm * 16 + rl + r;
        int col = col0 + wc * 64 + nn * 16 + cl;
        Cmat[(size_t)row * ldc + col] = acc[mm][nn][r];
      }
}

// ---------------- K2: merged qkv GEMM (section-ordered) --------------------
// bids 0..511: split-precision q,k tiles with R6's XCD swizzle (L2-local).
// bids 512..767: plain-bf16 v tiles with their own XCD swizzle.
// 768 blocks @ 32KB LDS -> 3 resident/CU; v blocks fill qk stall cycles.
__global__ __launch_bounds__(256) void gemm_qkv(
    const unsigned short* __restrict__ xh, const unsigned short* __restrict__ xl,
    const unsigned short* __restrict__ wah, const unsigned short* __restrict__ wal,
    float* __restrict__ qkv)
{
  __shared__ short lds[4 * 4096];
  int bid = blockIdx.x;               // 768
  if (bid < 512) {
    int swb = (bid & 7) * 64 + (bid >> 3);
    int bx = swb & 15, by = swb >> 4;   // 16 x 32 tiles over N=2048
    gemm_body<1>(lds, xh, xl, wah, wal, qkv,
                 CD, QKV_LD, by * 128, bx * 128);
  } else {
    int p = bid - 512;                  // 0..255
    int swb = (p & 7) * 32 + (p >> 3);
    int bx = swb & 7, by = swb >> 3;    // 8 x 32 tiles over N=1024
    gemm_body<0>(lds, xh, nullptr, wah + (size_t)2048 * CD, nullptr,
                 qkv + 2048, CD, QKV_LD, by * 128, bx * 128);
  }
}

// ---------------- K7: standalone projection GEMM ---------------------------
template<int SPLIT>
__global__ __launch_bounds__(256) void gemm_bt(
    const unsigned short* __restrict__ Ah, const unsigned short* __restrict__ Al,
    const unsigned short* __restrict__ Bh, const unsigned short* __restrict__ Bl,
    float* __restrict__ Cmat, int M, int N, int K, int ldc)
{
  constexpr int NT = SPLIT ? 4 : 2;
  __shared__ short lds[NT * 4096];
  const int nwg = gridDim.x;
  const int cpx = nwg >> 3;
  const int bid = blockIdx.x;
  const int swb = (bid & 7) * cpx + (bid >> 3);
  const int nbx = N >> 7;
  const int bx = swb % nbx;
  const int by = swb / nbx;
  gemm_body<SPLIT>(lds, Ah, Al, Bh, Bl, Cmat, K, ldc, by * 128, bx * 128);
}

// ---------------- K3a: per-seg partial sums (32-row segments) --------------
__global__ __launch_bounds__(256) void cs_part(const float* __restrict__ qkv,
                                               float* __restrict__ part) {
  int blk = blockIdx.x;                 // B*64*2 = 256
  int q   = blk & 1;
  int seg = (blk >> 1) & 63;
  int b   = blk >> 7;
  int c   = threadIdx.x * 4;            // 0..1023
  const float* src = qkv + (size_t)(b * T_ + seg * 32) * QKV_LD + CD + q * CD + c;
  float4 s = {0.f, 0.f, 0.f, 0.f};
  #pragma unroll 4
  for (int j = 0; j < 32; ++j) {
    float4 v = *(const float4*)(src + (size_t)j * QKV_LD);
    if (q == 0) {
      s.x += elu1(v.x); s.y += elu1(v.y); s.z += elu1(v.z); s.w += elu1(v.w);
    } else {
      s.x += v.x; s.y += v.y; s.z += v.z; s.w += v.w;
    }
  }
  *(float4*)(part + ((size_t)(b * 64 + seg) * 2048) + q * 1024 + c) = s;
}

// ---------------- K3b: exclusive prefix over 64 segs (reg-pipelined) ------
__global__ void cs_prefix(float* __restrict__ part) {
  int idx = blockIdx.x * 256 + threadIdx.x;      // B*2048 = 4096
  int b  = idx >> 11;
  int cc = idx & 2047;
  float v[64];
  #pragma unroll
  for (int s = 0; s < 64; ++s) v[s] = part[(size_t)(b * 64 + s) * 2048 + cc];
  float run = 0.f;
  #pragma unroll
  for (int s = 0; s < 64; ++s) { float t = v[s]; v[s] = run; run += t; }
  #pragma unroll
  for (int s = 0; s < 64; ++s) part[(size_t)(b * 64 + s) * 2048 + cc] = v[s];
}

// ---------------- K3c: final walk -> kcum / vcum --------------------------
__global__ __launch_bounds__(256) void cs_final(const float* __restrict__ qkv,
                                                const float* __restrict__ part,
                                                float* __restrict__ kcum,
                                                float* __restrict__ vcum) {
  int blk = blockIdx.x;                 // 256
  int q   = blk & 1;
  int seg = (blk >> 1) & 63;
  int b   = blk >> 7;
  int c   = threadIdx.x * 4;
  int h   = c >> 6, d = c & 63;
  const float* src = qkv + (size_t)(b * T_ + seg * 32) * QKV_LD + CD + q * CD + c;
  float* dst = (q == 0 ? kcum : vcum) + ((size_t)(b * NH_ + h) * T_ + seg * 32) * HS_ + d;
  float4 s = *(const float4*)(part + ((size_t)(b * 64 + seg) * 2048) + q * 1024 + c);
  #pragma unroll 4
  for (int j = 0; j < 32; ++j) {
    float4 v = *(const float4*)(src + (size_t)j * QKV_LD);
    if (q == 0) {
      s.x += elu1(v.x); s.y += elu1(v.y); s.z += elu1(v.z); s.w += elu1(v.w);
    } else {
      s.x += v.x; s.y += v.y; s.z += v.z; s.w += v.w;
    }
    *(float4*)(dst + (size_t)j * HS_) = s;
  }
}

// ---------------- K4: sorted-by-r set aggregates ---------------------------
__global__ void build_sets(const float* __restrict__ kcum, const float* __restrict__ vcum,
                           unsigned short* __restrict__ Ksh, unsigned short* __restrict__ Ksl,
                           float* __restrict__ Vs, int* __restrict__ r_srt) {
  int idx = blockIdx.x * 256 + threadIdx.x;    // B*NH*512*64
  if (idx >= B_ * NH_ * NSP * HS_) return;
  int d  = idx & 63;
  int s  = (idx >> 6) & (NSP - 1);
  int bh = idx >> (6 + 9);
  if (s == NSETS) {                            // padding entry
    size_t o = ((size_t)(bh << 9) + s) * HS_ + d;
    Ksh[o] = 0; Ksl[o] = 0; Vs[o] = 0.f;
    if (bh == 0 && d == 0) r_srt[s] = 0x7fffffff;
    return;
  }
  int lvl = 3, base = 0;
  while (s >= base + (T_ >> lvl)) { base += T_ >> lvl; ++lvl; }
  int i  = s - base;
  int m  = (i + 1) << lvl;
  int r  = m - 1;
  int li = i << lvl;
  int rank = lvl - 3;
  #pragma unroll
  for (int j = 3; j <= 11; ++j) rank += (m - 8) >> j;

  size_t rowr = ((size_t)bh * T_ + r) * HS_ + d;
  float kr = kcum[rowr], vr = vcum[rowr];
  if (li > 0) {
    size_t rowl = ((size_t)bh * T_ + li - 1) * HS_ + d;
    kr -= kcum[rowl];
    vr -= vcum[rowl];
  }
  size_t o = ((size_t)(bh << 9) + rank) * HS_ + d;
  unsigned short kh = f2bf(kr);
  Ksh[o] = kh;
  Ksl[o] = f2bf(kr - bf2f(kh));
  Vs[o]  = vr;
  if (bh == 0 && d == 0) r_srt[rank] = r;
}

// ---------------- K4b: Vst[bh][d][512] bf16 = transpose(Vs) ---------------
__global__ __launch_bounds__(256) void vst_transpose(
    const float* __restrict__ Vs, unsigned short* __restrict__ Vst) {
  __shared__ float tile[64][65];
  int bh = blockIdx.x >> 3;
  int s0 = (blockIdx.x & 7) * 64;
  int tid = threadIdx.x;
  int srow = tid >> 2, c0 = (tid & 3) * 16;
  const float* src = Vs + ((size_t)(bh << 9) + s0 + srow) * HS_ + c0;
  #pragma unroll
  for (int j = 0; j < 4; ++j) {
    float4 v = *(const float4*)(src + j * 4);
    tile[srow][c0 + j*4 + 0] = v.x; tile[srow][c0 + j*4 + 1] = v.y;
    tile[srow][c0 + j*4 + 2] = v.z; tile[srow][c0 + j*4 + 3] = v.w;
  }
  __syncthreads();
  int d = tid >> 2, sq = (tid & 3) * 16;
  short8 a, b;
  #pragma unroll
  for (int j = 0; j < 8; ++j) {
    a[j] = (short)f2bf(tile[sq + j][d]);
    b[j] = (short)f2bf(tile[sq + 8 + j][d]);
  }
  unsigned short* dst = Vst + ((size_t)(bh << 6) + d) * NSP + s0 + sq;
  *(short8*)dst = a;
  *(short8*)(dst + 8) = b;
}

// ---------------- K5: MFMA flash attention, 128 q-rows per block ----------
// 512 blocks = 32 bh x 16 row-blocks. Q hi/lo fragments in REGISTERS.
// K/V staged once per tile, amortized over 128 rows. Defer-max softmax.
__global__ __launch_bounds__(256) void attn_mfma(
    const float* __restrict__ qkv, const float* __restrict__ kcum,
    const float* __restrict__ vcum,
    const unsigned short* __restrict__ Ksh, const unsigned short* __restrict__ Ksl,
    const unsigned short* __restrict__ Vst, const int* __restrict__ r_srt,
    unsigned short* __restrict__ attnb)
{
  __shared__ short Pl[4 * 2048];        // 4 waves x 32 rows x 64 bf16 = 16KB
  __shared__ short KV[3 * 4096];        // Ksh|Ksl|Vst tiles, 8KB each
  __shared__ int   rs_lds[NSP];

  const int blk = blockIdx.x;           // 512
  const int xcd = blk & 7;
  const int j   = blk >> 3;             // 0..63
  const int bhx = j >> 4;
  const int bh  = xcd * 4 + bhx;
  const int rb  = ((j & 15) + bhx * 4) & 15;
  const int b = bh >> 4, h = bh & 15;
  const int t0 = rb * 128;
  const int tid = threadIdx.x;
  const int lane = tid & 63;
  const int w = tid >> 6;
  const int col = lane & 15;
  const int kgrp = (lane >> 4) * 8;
  const float scale = 0.125f;

  // staging geometry: per wave 6 gload16; lane l -> row i*8+(l>>3),
  // pre-swizzled source chunk ((l&7)^(l>>3)); LDS dest linear
  const int srow = lane >> 3;
  const int scsw = ((lane & 7) ^ srow) * 8;

  auto stage_tile = [&](int s0) {
    #pragma unroll
    for (int L = w * 6; L < w * 6 + 6; ++L) {
      int a = L >> 3, i = L & 7;
      const unsigned short* src;
      if (a == 0)      src = Ksh + ((size_t)(bh << 9) + s0 + i * 8 + srow) * 64 + scsw;
      else if (a == 1) src = Ksl + ((size_t)(bh << 9) + s0 + i * 8 + srow) * 64 + scsw;
      else             src = Vst + ((size_t)(bh << 6) + i * 8 + srow) * NSP + s0 + scsw;
      gload16(src, KV + a * 4096 + i * 512 + lane * 8);
    }
  };

  // ---- Q fragments: global -> split bf16 hi/lo in registers ----
  short8 qh[2][2], ql[2][2];
  #pragma unroll
  for (int rr = 0; rr < 2; ++rr) {
    int qrow = t0 + w * 32 + rr * 16 + col;
    const float* qr = qkv + (size_t)(b * T_ + qrow) * QKV_LD + h * HS_;
    #pragma unroll
    for (int ks = 0; ks < 2; ++ks) {
      float4 v0 = *(const float4*)(qr + kgrp + ks * 32);
      float4 v1 = *(const float4*)(qr + kgrp + ks * 32 + 4);
      float vv[8] = {v0.x, v0.y, v0.z, v0.w, v1.x, v1.y, v1.z, v1.w};
      #pragma unroll
      for (int jj = 0; jj < 8; ++jj) {
        unsigned short hi = f2bf(vv[jj]);
        qh[rr][ks][jj] = (short)hi;
        ql[rr][ks][jj] = (short)f2bf(vv[jj] - bf2f(hi));
      }
    }
  }
  for (int s = tid; s < NSP; s += 256) rs_lds[s] = r_srt[s];

  int rows[2][4];
  #pragma unroll
  for (int rr = 0; rr < 2; ++rr)
    #pragma unroll
    for (int r = 0; r < 4; ++r)
      rows[rr][r] = t0 + w * 32 + rr * 16 + (lane >> 4) * 4 + r;

  f32x4 O[2][4];
  float mrun[2][4], lsum[2][4];
  #pragma unroll
  for (int rr = 0; rr < 2; ++rr)
    #pragma unroll
    for (int f = 0; f < 4; ++f) {
      O[rr][f] = (f32x4){0.f, 0.f, 0.f, 0.f};
      mrun[rr][f] = NEGBIG; lsum[rr][f] = 0.f;
    }

  int nmax = 0;
  #pragma unroll
  for (int jj = 3; jj <= 11; ++jj) nmax += (t0 + 128) >> jj;
  const int ntiles = (nmax + 63) >> 6;

  for (int tile = 0; tile < ntiles; ++tile) {
    const int s0 = tile * 64;
    stage_tile(s0);
    __syncthreads();     // drains gload vmcnt(0)

    f32x4 S[2][4];
    #pragma unroll
    for (int rr = 0; rr < 2; ++rr)
      #pragma unroll
      for (int f = 0; f < 4; ++f) S[rr][f] = (f32x4){0.f, 0.f, 0.f, 0.f};

    #pragma unroll
    for (int ks = 0; ks < 2; ++ks) {
      int chnk = (lane >> 4) + ks * 4;
      #pragma unroll
      for (int f = 0; f < 4; ++f) {
        int so = f * 16 + col;
        int kb = so * 128 + ((chnk ^ (so & 7)) << 4);
        short8 bHv = *(const short8*)((const char*)KV + kb);
        short8 bLv = *(const short8*)((const char*)KV + 8192 + kb);
        #pragma unroll
        for (int rr = 0; rr < 2; ++rr) {
          S[rr][f] = __builtin_amdgcn_mfma_f32_16x16x32_bf16(qh[rr][ks], bHv, S[rr][f], 0, 0, 0);
          S[rr][f] = __builtin_amdgcn_mfma_f32_16x16x32_bf16(qh[rr][ks], bLv, S[rr][f], 0, 0, 0);
          S[rr][f] = __builtin_amdgcn_mfma_f32_16x16x32_bf16(ql[rr][ks], bHv, S[rr][f], 0, 0, 0);
        }
      }
    }

    int rsv[4];
    #pragma unroll
    for (int f = 0; f < 4; ++f) rsv[f] = rs_lds[s0 + f * 16 + col];

    // masked logits in place
    #pragma unroll
    for (int rr = 0; rr < 2; ++rr)
      #pragma unroll
      for (int f = 0; f < 4; ++f)
        #pragma unroll
        for (int r = 0; r < 4; ++r)
          S[rr][f][r] = (rsv[f] > rows[rr][r]) ? NEGBIG : S[rr][f][r] * scale;

    // ---- fast-path check across all 8 row-groups ----
    float mx[2][4];
    int pred = 1;
    #pragma unroll
    for (int rr = 0; rr < 2; ++rr)
      #pragma unroll
      for (int r = 0; r < 4; ++r) {
        mx[rr][r] = fmaxf(fmaxf(S[rr][0][r], S[rr][1][r]),
                          fmaxf(S[rr][2][r], S[rr][3][r]));
        pred &= (mx[rr][r] <= mrun[rr][r] + 8.f);
      }
    if (!__all(pred)) {
      #pragma unroll
      for (int rr = 0; rr < 2; ++rr)
        #pragma unroll
        for (int r = 0; r < 4; ++r) {
          float mt = mx[rr][r];
          mt = fmaxf(mt, __shfl_xor(mt, 1));
          mt = fmaxf(mt, __shfl_xor(mt, 2));
          mt = fmaxf(mt, __shfl_xor(mt, 4));
          mt = fmaxf(mt, __shfl_xor(mt, 8));
          float mv = fmaxf(mrun[rr][r], mt);
          float fs = __expf(mrun[rr][r] - mv);
          lsum[rr][r] *= fs;
          #pragma unroll
          for (int f = 0; f < 4; ++f) O[rr][f][r] *= fs;
          mrun[rr][r] = mv;
        }
    }

    // ---- P = exp(z - mrun), masked; lane-local sum; bf16 to LDS ----
    char* pw = (char*)Pl + w * 4096;
    #pragma unroll
    for (int rr = 0; rr < 2; ++rr)
      #pragma unroll
      for (int r = 0; r < 4; ++r) {
        int rowr = rr * 16 + (lane >> 4) * 4 + r;
        int rswz = (rowr & 7) << 4;
        #pragma unroll
        for (int f = 0; f < 4; ++f) {
          float p = __expf(S[rr][f][r] - mrun[rr][r]);
          p = (rsv[f] > rows[rr][r]) ? 0.f : p;
          lsum[rr][r] += p;
          int addr = (rowr * 128 + (f * 16 + col) * 2) ^ rswz;
          *(unsigned short*)(pw + addr) = f2bf(p);
        }
      }

    // ---- PV MFMA ----
    #pragma unroll
    for (int ks = 0; ks < 2; ++ks) {
      int chnk = (lane >> 4) + ks * 4;
      int pb0 = (col * 128 + (kgrp + ks * 32) * 2) ^ ((col & 7) << 4);
      short8 pa0 = *(const short8*)(pw + pb0);
      short8 pa1 = *(const short8*)(pw + 2048 + pb0);   // rows 16..31
      #pragma unroll
      for (int f = 0; f < 4; ++f) {
        int dr = f * 16 + col;
        short8 bv = *(const short8*)((const char*)KV + 16384 + dr * 128 + ((chnk ^ (dr & 7)) << 4));
        O[0][f] = __builtin_amdgcn_mfma_f32_16x16x32_bf16(pa0, bv, O[0][f], 0, 0, 0);
        O[1][f] = __builtin_amdgcn_mfma_f32_16x16x32_bf16(pa1, bv, O[1][f], 0, 0, 0);
      }
    }

    __syncthreads();     // all waves done reading KV before next stage
  }

  // ---- deferred cross-lane sum of lsum -> lrun ----
  float lrun[2][4];
  #pragma unroll
  for (int rr = 0; rr < 2; ++rr)
    #pragma unroll
    for (int r = 0; r < 4; ++r) {
      float l = lsum[rr][r];
      l += __shfl_xor(l, 1);
      l += __shfl_xor(l, 2);
      l += __shfl_xor(l, 4);
      l += __shfl_xor(l, 8);
      lrun[rr][r] = l;
    }

  // ---- tail term: interval [t&~7, t] with q_phi, per-row VALU ----
  float ztail[2];
  #pragma unroll
  for (int rr = 0; rr < 2; ++rr) {
    int trow = lane >> 2;
    int t = t0 + w * 32 + rr * 16 + trow;
    int d0 = (lane & 3) * 16;
    const float* qr = qkv + (size_t)(b * T_ + t) * QKV_LD + h * HS_ + d0;
    float qv[16];
    #pragma unroll
    for (int jj = 0; jj < 4; ++jj) {
      float4 v = *(const float4*)(qr + jj * 4);
      qv[jj*4+0] = v.x; qv[jj*4+1] = v.y; qv[jj*4+2] = v.z; qv[jj*4+3] = v.w;
    }
    int lt = t & ~7;
    const float* kc1 = kcum + ((size_t)bh * T_ + t) * HS_ + d0;
    float kt[16];
    if (lt > 0) {
      const float* kc0 = kcum + ((size_t)bh * T_ + (lt - 1)) * HS_ + d0;
      #pragma unroll
      for (int jj = 0; jj < 16; ++jj) kt[jj] = kc1[jj] - kc0[jj];
    } else {
      #pragma unroll
      for (int jj = 0; jj < 16; ++jj) kt[jj] = kc1[jj];
    }
    float z = 0.f;
    #pragma unroll
    for (int jj = 0; jj < 16; ++jj) {
      float qp = qv[jj] > 0.f ? qv[jj] + 1.f : __expf(qv[jj]);
      z += qp * kt[jj];
    }
    z += __shfl_xor(z, 1);
    z += __shfl_xor(z, 2);
    ztail[rr] = z * scale;
  }

  #pragma unroll
  for (int rr = 0; rr < 2; ++rr)
    #pragma unroll
    for (int r = 0; r < 4; ++r) {
      float zt = __shfl(ztail[rr], ((lane >> 4) * 4 + r) * 4);
      float mv = fmaxf(mrun[rr][r], zt);
      float fs = __expf(mrun[rr][r] - mv);     // mrun=NEGBIG -> 0
      float pwgt = __expf(zt - mv);
      lrun[rr][r] = lrun[rr][r] * fs + pwgt;
      int tr = rows[rr][r];
      int ltr = tr & ~7;
      #pragma unroll
      for (int f = 0; f < 4; ++f) {
        int d = f * 16 + col;
        float v1 = vcum[((size_t)bh * T_ + tr) * HS_ + d];
        float vt = (ltr > 0) ? v1 - vcum[((size_t)bh * T_ + (ltr - 1)) * HS_ + d] : v1;
        O[rr][f][r] = O[rr][f][r] * fs + pwgt * vt;
      }
    }

  #pragma unroll
  for (int rr = 0; rr < 2; ++rr)
    #pragma unroll
    for (int r = 0; r < 4; ++r) {
      float inv = 1.f / lrun[rr][r];
      unsigned short* orow = attnb + (size_t)(b * T_ + rows[rr][r]) * CD + h * HS_;
      #pragma unroll
      for (int f = 0; f < 4; ++f)
        orow[f * 16 + col] = f2bf(O[rr][f][r] * inv);
    }
}

// --------------------------------------------------------------------------
extern "C" void kernel_launch(void* const* d_in, const int* in_sizes, int n_in,
                              void* d_out, int out_size, void* d_ws, size_t ws_size,
                              hipStream_t stream) {
  const float* x  = (const float*)d_in[0];   // [B,T,C]
  const float* Wa = (const float*)d_in[1];   // [3C,C]
  const float* Wp = (const float*)d_in[2];   // [C,C]
  float* out = (float*)d_out;                // [B,T,C]

  char* ws = (char*)d_ws;
  size_t off = 0;
  auto alloc = [&](size_t bytes) -> char* {
    char* p = ws + off;
    off += (bytes + 255) & ~(size_t)255;
    return p;
  };

  const int M = B_ * T_;                     // 4096
  float* qkv  = (float*)alloc((size_t)M * QKV_LD * 4);            // 50.3 MB
  float* kcum = (float*)alloc((size_t)B_ * NH_ * T_ * HS_ * 4);   // 16.8 MB
  float* vcum = (float*)alloc((size_t)B_ * NH_ * T_ * HS_ * 4);   // 16.8 MB
  float* part = (float*)alloc((size_t)B_ * 64 * 2048 * 4);        // 1 MB
  unsigned short* wph = (unsigned short*)alloc((size_t)CD * CD * 2);

  // regionA: x_hi/x_lo (live through gemm_qkv), then sorted set arrays
  char* regionA = alloc((size_t)16777216);
  unsigned short* xh = (unsigned short*)regionA;
  unsigned short* xl = (unsigned short*)(regionA + (size_t)M * CD * 2);
  const size_t SETS_ELEMS = (size_t)B_ * NH_ * NSP * HS_;          // 2M
  unsigned short* Ksh = (unsigned short*)regionA;                  // 4 MB
  unsigned short* Ksl = Ksh + SETS_ELEMS;                          // 4 MB
  float*          Vss = (float*)(regionA + 2 * SETS_ELEMS * 2);    // 8 MB
  unsigned short* Vst = (unsigned short*)(regionA + 2 * SETS_ELEMS * 2 + SETS_ELEMS * 4);
  int*            r_srt = (int*)(regionA + 2 * SETS_ELEMS * 2 + SETS_ELEMS * 4 + SETS_ELEMS * 2);

  // regionB: Wa_hi/Wa_lo (live through gemm_qkv), then attn bf16 output
  char* regionB = alloc((size_t)12582912);
  unsigned short* wah = (unsigned short*)regionB;
  unsigned short* wal = (unsigned short*)(regionB + (size_t)3 * CD * CD * 2);
  unsigned short* attnb = (unsigned short*)regionB;

  // K1: fused splits (Wa v-rows get hi only)
  split3_kernel<<<dim3(32768), dim3(256), 0, stream>>>(
      x, Wa, Wp, xh, xl, wah, wal, wph);

  // K2: merged qkv GEMM (section-ordered: 512 qk-split + 256 v-plain)
  gemm_qkv<<<dim3(768), dim3(256), 0, stream>>>(xh, xl, wah, wal, qkv);

  // K3: phi + cumsums (32-row segments, 256 blocks each)
  cs_part<<<dim3(B_ * 64 * 2), dim3(256), 0, stream>>>(qkv, part);
  cs_prefix<<<dim3(B_ * 2048 / 256), dim3(256), 0, stream>>>(part);
  cs_final<<<dim3(B_ * 64 * 2), dim3(256), 0, stream>>>(qkv, part, kcum, vcum);

  // K4: sorted set aggregates (reuses regionA — xh/xl dead after gemm_qkv)
  build_sets<<<dim3((B_ * NH_ * NSP * HS_) / 256), dim3(256), 0, stream>>>(
      kcum, vcum, Ksh, Ksl, Vss, r_srt);
  vst_transpose<<<dim3(B_ * NH_ * (NSP / 64)), dim3(256), 0, stream>>>(Vss, Vst);

  // K5: MFMA attention, 128 rows/block (writes bf16 into regionB)
  attn_mfma<<<dim3(512), dim3(256), 0, stream>>>(
      qkv, kcum, vcum, Ksh, Ksl, Vst, r_srt, attnb);

  // K7: out = attn @ Wp^T
  gemm_bt<0><<<dim3((CD / 128) * (M / 128)), dim3(256), 0, stream>>>(
      attnb, (const unsigned short*)nullptr, wph, (const unsigned short*)nullptr,
      out, M, CD, CD, CD);
}